// Round 9
// baseline (45.147 us; speedup 1.0000x reference)
//
#include <hip/hip_runtime.h>
#include <cstdint>

#define OUTF 12288
#define INF  4096
#define NG   32
#define BATCH 8

#define BLOCK 512
#define WAVES 8
#define RPW 3                  // rows per wave, consumed SEQUENTIALLY
#define RPB (WAVES*RPW)        // 24 rows per block
#define NBLK (OUTF/RPB)        // 512 blocks -> 2 blocks/CU

typedef _Float16 half2_t __attribute__((ext_vector_type(2)));

__device__ __forceinline__ float dot2(half2_t a, half2_t b, float c) {
#if __has_builtin(__builtin_amdgcn_fdot2)
    return __builtin_amdgcn_fdot2(a, b, c, false);
#else
    return c + (float)(a.x) * (float)(b.x) + (float)(a.y) * (float)(b.y);
#endif
}
__device__ __forceinline__ half2_t pk16(float a, float b) {
    return __builtin_bit_cast(half2_t, __builtin_amdgcn_cvt_pkrtz(a, b));
}

__global__ __launch_bounds__(BLOCK, 4) void qlin_kernel(
    const float* __restrict__ x,       // [8][4096] fp32
    const int*   __restrict__ qc,      // [12288][2048] int32, one packed byte/elem
    const float* __restrict__ scales,  // [12288][32]
    const float* __restrict__ zeros,   // [12288][32]
    const float* __restrict__ bias,    // [12288]
    float* __restrict__ out)           // [8][12288]
{
    __shared__ uint4 xs[4096];         // 64 KiB: [b][512] slots of 8 fp16, linear

    const int tid  = threadIdx.x;
    const int wave = tid >> 6;
    const int lane = tid & 63;
    const int row0 = blockIdx.x * RPB + wave * RPW;

    // The wave's 3 rows are CONSECUTIVE in qc -> its whole 24 KB q-region is
    // linear. Chunk c (0..11): row = c>>2, cc = c&3; lane's 32 B at
    // qbase + (c>>2)*2048 + (c&3)*512 (int32 elems); wave chunk = 2 KB contig.
    const int* qbase = qc + row0 * 2048 + lane * 8;

    // ---- prologue: issue q chunks 0,1 FIRST (critical-path stream) ----
    uint4 qb[3][2];
    qb[0][0] = *reinterpret_cast<const uint4*>(qbase + 0);
    qb[0][1] = *reinterpret_cast<const uint4*>(qbase + 4);
    qb[1][0] = *reinterpret_cast<const uint4*>(qbase + 512);
    qb[1][1] = *reinterpret_cast<const uint4*>(qbase + 516);

    // ---- stage ALL of x as fp16 (round-5 proven) ----
    #pragma unroll
    for (int i = 0; i < 8; ++i) {
        const float4 v0 = *reinterpret_cast<const float4*>(x + i * INF + tid * 8);
        const float4 v1 = *reinterpret_cast<const float4*>(x + i * INF + tid * 8 + 4);
        uint4 w;
        w.x = __builtin_bit_cast(uint32_t, pk16(v0.x, v0.y));
        w.y = __builtin_bit_cast(uint32_t, pk16(v0.z, v0.w));
        w.z = __builtin_bit_cast(uint32_t, pk16(v1.x, v1.y));
        w.w = __builtin_bit_cast(uint32_t, pk16(v1.z, v1.w));
        xs[i * 512 + tid] = w;
    }

    // ---- preload sc / (-zp*sc): chunk cc of row r -> group cc*8 + (lane>>3) ----
    float sc_[RPW][4], nz_[RPW][4];
    #pragma unroll
    for (int r = 0; r < RPW; ++r) {
        #pragma unroll
        for (int cc = 0; cc < 4; ++cc) {
            const int a = (row0 + r) * NG + cc * 8 + (lane >> 3);
            const float s = scales[a];
            sc_[r][cc] = s;
            nz_[r][cc] = -zeros[a] * s;
        }
    }

    float y[RPW][BATCH];
    #pragma unroll
    for (int r = 0; r < RPW; ++r)
        #pragma unroll
        for (int b = 0; b < BATCH; ++b) y[r][b] = 0.f;

    __syncthreads();   // the only barrier

    #pragma unroll
    for (int c = 0; c < 12; ++c) {
        const int r  = c >> 2;
        const int cc = c & 3;

        // prefetch chunk c+2 (address continues linearly across row boundary)
        if (c < 10) {
            const int c2  = c + 2;
            const int off = (c2 >> 2) * 2048 + (c2 & 3) * 512;
            qb[c2 % 3][0] = *reinterpret_cast<const uint4*>(qbase + off);
            qb[c2 % 3][1] = *reinterpret_cast<const uint4*>(qbase + off + 4);
        }

        const uint4 t0 = qb[c % 3][0];
        const uint4 t1 = qb[c % 3][1];
        const float s_ = sc_[r][cc];
        const float n_ = nz_[r][cc];

        // 8 ints -> 16 pre-scaled fp16 weights (hi nibble = even k)
        half2_t wp[8];
        {
            const uint32_t e[8] = {t0.x, t0.y, t0.z, t0.w, t1.x, t1.y, t1.z, t1.w};
            #pragma unroll
            for (int i = 0; i < 8; ++i)
                wp[i] = pk16(fmaf((float)((e[i] >> 4) & 0xFu), s_, n_),
                             fmaf((float)( e[i]       & 0xFu), s_, n_));
        }

        // lane covers k [cc*1024 + lane*16, +16): fp16 slots cc*128+lane*2, +1
        const int sbase = cc * 128 + lane * 2;
        #pragma unroll
        for (int b = 0; b < BATCH; ++b) {
            const uint4 v0 = xs[b * 512 + sbase];
            const uint4 v1 = xs[b * 512 + sbase + 1];
            float acc = y[r][b];
            acc = dot2(wp[0], __builtin_bit_cast(half2_t, v0.x), acc);
            acc = dot2(wp[1], __builtin_bit_cast(half2_t, v0.y), acc);
            acc = dot2(wp[2], __builtin_bit_cast(half2_t, v0.z), acc);
            acc = dot2(wp[3], __builtin_bit_cast(half2_t, v0.w), acc);
            acc = dot2(wp[4], __builtin_bit_cast(half2_t, v1.x), acc);
            acc = dot2(wp[5], __builtin_bit_cast(half2_t, v1.y), acc);
            acc = dot2(wp[6], __builtin_bit_cast(half2_t, v1.z), acc);
            acc = dot2(wp[7], __builtin_bit_cast(half2_t, v1.w), acc);
            y[r][b] = acc;
        }
    }

    // 64-lane butterfly; lane (r*8+b) keeps value (r,b)
    float keep = 0.f;
    #pragma unroll
    for (int r = 0; r < RPW; ++r) {
        #pragma unroll
        for (int b = 0; b < BATCH; ++b) {
            float v = y[r][b];
            #pragma unroll
            for (int m = 1; m < 64; m <<= 1) v += __shfl_xor(v, m, 64);
            if (lane == r * 8 + b) keep = v;
        }
    }
    if (lane < RPW * BATCH) {
        const int r = lane >> 3, b = lane & 7;
        const int o = row0 + r;
        out[b * OUTF + o] = keep + bias[o];
    }
}

extern "C" void kernel_launch(void* const* d_in, const int* in_sizes, int n_in,
                              void* d_out, int out_size, void* d_ws, size_t ws_size,
                              hipStream_t stream) {
    const float* x      = (const float*)d_in[0];
    const int*   qcodes = (const int*)  d_in[1];
    const float* scales = (const float*)d_in[2];
    const float* zeros  = (const float*)d_in[3];
    const float* bias   = (const float*)d_in[4];
    float* out = (float*)d_out;

    qlin_kernel<<<NBLK, BLOCK, 0, stream>>>(x, qcodes, scales, zeros, bias, out);
}

// Round 11
// 31.530 us; speedup vs baseline: 1.4319x; 1.4319x over previous
//
#include <hip/hip_runtime.h>
#include <cstdint>

#define OUTF 12288
#define INF  4096
#define NG   32
#define BATCH 8

#define BLOCK 512
#define WAVES 8
#define RPW 3              // output rows per wave
#define RPB (WAVES*RPW)    // 24 rows per block
#define NBLK (OUTF/RPB)    // 512 blocks -> 2 blocks/CU (LDS-capped)

typedef _Float16 half2_t __attribute__((ext_vector_type(2)));
typedef unsigned int uivec4 __attribute__((ext_vector_type(4)));

__device__ __forceinline__ float dot2(half2_t a, half2_t b, float c) {
#if __has_builtin(__builtin_amdgcn_fdot2)
    return __builtin_amdgcn_fdot2(a, b, c, false);
#else
    return c + (float)(a.x) * (float)(b.x) + (float)(a.y) * (float)(b.y);
#endif
}

__device__ __forceinline__ half2_t pk16(float a, float b) {
    return __builtin_bit_cast(half2_t, __builtin_amdgcn_cvt_pkrtz(a, b));
}

// non-temporal 16B load: q-stream is read-once -> nt flag, keep caches for x
__device__ __forceinline__ uivec4 ntload4(const int* p) {
    return __builtin_nontemporal_load(reinterpret_cast<const uivec4*>(p));
}

__global__ __launch_bounds__(BLOCK, 4) void qlin_kernel(
    const float* __restrict__ x,       // [8][4096] fp32
    const int*   __restrict__ qc,      // [12288][2048] int32, one packed byte/elem
    const float* __restrict__ scales,  // [12288][32]
    const float* __restrict__ zeros,   // [12288][32]
    const float* __restrict__ bias,    // [12288]
    float* __restrict__ out)           // [8][12288]
{
    __shared__ uint4 xs[4096];         // 64 KiB: [b][512] slots of 8 fp16, LINEAR
                                       // read slot = h*64+lane (16B lane-stride:
                                       // consecutive disjoint bank-quads, 0-conflict)

    const int tid  = threadIdx.x;
    const int wave = tid >> 6;
    const int lane = tid & 63;
    const int row0 = blockIdx.x * RPB + wave * RPW;

    // q row bases: at step h, lane covers k in [h*512 + lane*8, +8)
    // -> ints qp[r] + h*256 + [0,4) ; lane-stride 16B, wave load = 1KB contig
    const int* qp[RPW];
    #pragma unroll
    for (int r = 0; r < RPW; ++r)
        qp[r] = qc + (row0 + r) * 2048 + lane * 4;

    // ---- q prologue FIRST: own the front of the VMEM queue ----
    uivec4 tA[RPW], tB[RPW];
    #pragma unroll
    for (int r = 0; r < RPW; ++r) {
        tA[r] = ntload4(qp[r]);
        tB[r] = ntload4(qp[r] + 256);
    }

    // ---- stage ALL of x as fp16, once, linear layout ----
    #pragma unroll
    for (int i = 0; i < 8; ++i) {
        const float4 v0 = *reinterpret_cast<const float4*>(x + i * INF + tid * 8);
        const float4 v1 = *reinterpret_cast<const float4*>(x + i * INF + tid * 8 + 4);
        uint4 w;
        w.x = __builtin_bit_cast(uint32_t, pk16(v0.x, v0.y));
        w.y = __builtin_bit_cast(uint32_t, pk16(v0.z, v0.w));
        w.z = __builtin_bit_cast(uint32_t, pk16(v1.x, v1.y));
        w.w = __builtin_bit_cast(uint32_t, pk16(v1.z, v1.w));
        xs[i * 512 + tid] = w;
    }

    // scale/zero bases: group g = h*4 + (lane>>4)
    const float* scb[RPW];
    const float* zpb[RPW];
    #pragma unroll
    for (int r = 0; r < RPW; ++r) {
        const int o = row0 + r;
        scb[r] = scales + o * NG + (lane >> 4);
        zpb[r] = zeros  + o * NG + (lane >> 4);
    }

    float sA[RPW], nzA[RPW], sB[RPW], nzB[RPW];
    #pragma unroll
    for (int r = 0; r < RPW; ++r) {
        sA[r]  = scb[r][0];
        nzA[r] = -zpb[r][0] * sA[r];
    }

    float y[RPW][BATCH];
    #pragma unroll
    for (int r = 0; r < RPW; ++r)
        #pragma unroll
        for (int b = 0; b < BATCH; ++b) y[r][b] = 0.f;

    __syncthreads();   // the ONLY barrier

    #pragma unroll
    for (int h = 0; h < 8; ++h) {
        // prefetch q for h+2, sc/zp for h+1
        uivec4 tN[RPW];
        if (h < 6) {
            #pragma unroll
            for (int r = 0; r < RPW; ++r)
                tN[r] = ntload4(qp[r] + (h + 2) * 256);
        }
        if (h < 7) {
            #pragma unroll
            for (int r = 0; r < RPW; ++r) {
                sB[r]  = scb[r][(h + 1) * 4];
                nzB[r] = -zpb[r][(h + 1) * 4] * sB[r];
            }
        }

        // unpack + pre-scale: int e -> k-pair (hi nibble = even k)
        half2_t wp[RPW][4];
        #pragma unroll
        for (int r = 0; r < RPW; ++r) {
            #pragma unroll
            for (int e = 0; e < 4; ++e) {
                const uint32_t ei = tA[r][e];
                const float hi = (float)((ei >> 4) & 0xFu);
                const float lo = (float)( ei       & 0xFu);
                wp[r][e] = pk16(fmaf(hi, sA[r], nzA[r]),
                                fmaf(lo, sA[r], nzA[r]));
            }
        }

        const int slot = h * 64 + lane;   // 16B lane-stride: conflict-free
        #pragma unroll
        for (int b = 0; b < BATCH; ++b) {
            const uint4 v = xs[b * 512 + slot];
            const half2_t x0 = __builtin_bit_cast(half2_t, v.x);
            const half2_t x1 = __builtin_bit_cast(half2_t, v.y);
            const half2_t x2 = __builtin_bit_cast(half2_t, v.z);
            const half2_t x3 = __builtin_bit_cast(half2_t, v.w);
            #pragma unroll
            for (int r = 0; r < RPW; ++r) {
                y[r][b] = dot2(wp[r][0], x0, y[r][b]);
                y[r][b] = dot2(wp[r][1], x1, y[r][b]);
                y[r][b] = dot2(wp[r][2], x2, y[r][b]);
                y[r][b] = dot2(wp[r][3], x3, y[r][b]);
            }
        }

        // rotate pipelines
        #pragma unroll
        for (int r = 0; r < RPW; ++r) {
            tA[r] = tB[r];
            if (h < 6) tB[r] = tN[r];
            if (h < 7) { sA[r] = sB[r]; nzA[r] = nzB[r]; }
        }
    }

    // 64-lane butterfly; lane (r*8+b) keeps value (r,b)
    float keep = 0.f;
    #pragma unroll
    for (int r = 0; r < RPW; ++r) {
        #pragma unroll
        for (int b = 0; b < BATCH; ++b) {
            float v = y[r][b];
            #pragma unroll
            for (int m = 1; m < 64; m <<= 1) v += __shfl_xor(v, m, 64);
            if (lane == r * 8 + b) keep = v;
        }
    }
    if (lane < RPW * BATCH) {
        const int r = lane >> 3, b = lane & 7;
        const int o = row0 + r;
        out[b * OUTF + o] = keep + bias[o];
    }
}

extern "C" void kernel_launch(void* const* d_in, const int* in_sizes, int n_in,
                              void* d_out, int out_size, void* d_ws, size_t ws_size,
                              hipStream_t stream) {
    const float* x      = (const float*)d_in[0];
    const int*   qcodes = (const int*)  d_in[1];
    const float* scales = (const float*)d_in[2];
    const float* zeros  = (const float*)d_in[3];
    const float* bias   = (const float*)d_in[4];
    float* out = (float*)d_out;

    qlin_kernel<<<NBLK, BLOCK, 0, stream>>>(x, qcodes, scales, zeros, bias, out);
}

// Round 12
// 27.516 us; speedup vs baseline: 1.6407x; 1.1459x over previous
//
#include <hip/hip_runtime.h>
#include <cstdint>

#define OUTF 12288
#define INF  4096
#define NG   32
#define BATCH 8

#define BLOCK 512
#define WAVES 8
#define RPW 3              // output rows per wave
#define RPB (WAVES*RPW)    // 24 rows per block
#define NBLK (OUTF/RPB)    // 512 blocks -> 2 blocks/CU (LDS-capped)

typedef _Float16 half2_t __attribute__((ext_vector_type(2)));

__device__ __forceinline__ float dot2(half2_t a, half2_t b, float c) {
#if __has_builtin(__builtin_amdgcn_fdot2)
    return __builtin_amdgcn_fdot2(a, b, c, false);
#else
    return c + (float)(a.x) * (float)(b.x) + (float)(a.y) * (float)(b.y);
#endif
}

__device__ __forceinline__ half2_t pk16(float a, float b) {
    return __builtin_bit_cast(half2_t, __builtin_amdgcn_cvt_pkrtz(a, b));
}

__global__ __launch_bounds__(BLOCK, 4) void qlin_kernel(
    const float* __restrict__ x,       // [8][4096] fp32
    const int*   __restrict__ qc,      // [12288][2048] int32, one packed byte/elem
    const float* __restrict__ scales,  // [12288][32]
    const float* __restrict__ zeros,   // [12288][32]
    const float* __restrict__ bias,    // [12288]
    float* __restrict__ out)           // [8][12288]
{
    __shared__ uint4 xs[4096];         // 64 KiB: [b][512] slots of 8 fp16, LINEAR

    const int tid  = threadIdx.x;
    const int wave = tid >> 6;
    const int lane = tid & 63;
    const int row0 = blockIdx.x * RPB + wave * RPW;

    // ---- stage ALL of x as fp16, once, linear layout ----
    #pragma unroll
    for (int i = 0; i < 8; ++i) {
        const float4 v0 = *reinterpret_cast<const float4*>(x + i * INF + tid * 8);
        const float4 v1 = *reinterpret_cast<const float4*>(x + i * INF + tid * 8 + 4);
        uint4 w;
        w.x = __builtin_bit_cast(uint32_t, pk16(v0.x, v0.y));
        w.y = __builtin_bit_cast(uint32_t, pk16(v0.z, v0.w));
        w.z = __builtin_bit_cast(uint32_t, pk16(v1.x, v1.y));
        w.w = __builtin_bit_cast(uint32_t, pk16(v1.z, v1.w));
        xs[i * 512 + tid] = w;
    }

    // per-row bases: at step h, lane covers k in [h*512 + lane*8, +8)
    // (one quant group: g = h*4 + (lane>>4)); q ints: h*256 + lane*4 .. +4
    const int* qp[RPW];
    const float* scb[RPW];
    const float* zpb[RPW];
    #pragma unroll
    for (int r = 0; r < RPW; ++r) {
        const int o = row0 + r;
        qp[r]  = qc + o * 2048 + lane * 4;
        scb[r] = scales + o * NG + (lane >> 4);
        zpb[r] = zeros  + o * NG + (lane >> 4);
    }

    // prologue: q for h=0,1 ; sc/zp for h=0 (w = q*sc + (-zp*sc))
    uint4 tA[RPW], tB[RPW];
    float sA[RPW], nzA[RPW], sB[RPW], nzB[RPW];
    #pragma unroll
    for (int r = 0; r < RPW; ++r) {
        tA[r]  = *reinterpret_cast<const uint4*>(qp[r]);
        tB[r]  = *reinterpret_cast<const uint4*>(qp[r] + 256);
        sA[r]  = scb[r][0];
        nzA[r] = -zpb[r][0] * sA[r];
    }

    float y[RPW][BATCH];
    #pragma unroll
    for (int r = 0; r < RPW; ++r)
        #pragma unroll
        for (int b = 0; b < BATCH; ++b) y[r][b] = 0.f;

    __syncthreads();   // the ONLY barrier

    #pragma unroll
    for (int h = 0; h < 8; ++h) {
        // prefetch q for h+2, sc/zp for h+1
        uint4 tN[RPW];
        if (h < 6) {
            #pragma unroll
            for (int r = 0; r < RPW; ++r)
                tN[r] = *reinterpret_cast<const uint4*>(qp[r] + (h + 2) * 256);
        }
        if (h < 7) {
            #pragma unroll
            for (int r = 0; r < RPW; ++r) {
                sB[r]  = scb[r][(h + 1) * 4];
                nzB[r] = -zpb[r][(h + 1) * 4] * sB[r];
            }
        }

        // unpack + pre-scale: int e -> k-pair (hi nibble = even k)
        half2_t wp[RPW][4];
        #pragma unroll
        for (int r = 0; r < RPW; ++r) {
            #pragma unroll
            for (int e = 0; e < 4; ++e) {
                const uint32_t ei = (e == 0) ? tA[r].x : (e == 1) ? tA[r].y
                                 : (e == 2) ? tA[r].z : tA[r].w;
                const float hi = (float)((ei >> 4) & 0xFu);
                const float lo = (float)( ei       & 0xFu);
                wp[r][e] = pk16(fmaf(hi, sA[r], nzA[r]),
                                fmaf(lo, sA[r], nzA[r]));
            }
        }

        const int slot = h * 64 + lane;   // lane-consecutive: conflict-free
        #pragma unroll
        for (int b = 0; b < BATCH; ++b) {
            const uint4 v = xs[b * 512 + slot];
            const half2_t x0 = __builtin_bit_cast(half2_t, v.x);
            const half2_t x1 = __builtin_bit_cast(half2_t, v.y);
            const half2_t x2 = __builtin_bit_cast(half2_t, v.z);
            const half2_t x3 = __builtin_bit_cast(half2_t, v.w);
            #pragma unroll
            for (int r = 0; r < RPW; ++r) {
                y[r][b] = dot2(wp[r][0], x0, y[r][b]);
                y[r][b] = dot2(wp[r][1], x1, y[r][b]);
                y[r][b] = dot2(wp[r][2], x2, y[r][b]);
                y[r][b] = dot2(wp[r][3], x3, y[r][b]);
            }
        }

        // rotate pipelines
        #pragma unroll
        for (int r = 0; r < RPW; ++r) {
            tA[r] = tB[r];
            if (h < 6) tB[r] = tN[r];
            if (h < 7) { sA[r] = sB[r]; nzA[r] = nzB[r]; }
        }
    }

    // 64-lane butterfly; lane (r*8+b) keeps value (r,b)
    float keep = 0.f;
    #pragma unroll
    for (int r = 0; r < RPW; ++r) {
        #pragma unroll
        for (int b = 0; b < BATCH; ++b) {
            float v = y[r][b];
            #pragma unroll
            for (int m = 1; m < 64; m <<= 1) v += __shfl_xor(v, m, 64);
            if (lane == r * 8 + b) keep = v;
        }
    }
    if (lane < RPW * BATCH) {
        const int r = lane >> 3, b = lane & 7;
        const int o = row0 + r;
        out[b * OUTF + o] = keep + bias[o];
    }
}

extern "C" void kernel_launch(void* const* d_in, const int* in_sizes, int n_in,
                              void* d_out, int out_size, void* d_ws, size_t ws_size,
                              hipStream_t stream) {
    const float* x      = (const float*)d_in[0];
    const int*   qcodes = (const int*)  d_in[1];
    const float* scales = (const float*)d_in[2];
    const float* zeros  = (const float*)d_in[3];
    const float* bias   = (const float*)d_in[4];
    float* out = (float*)d_out;

    qlin_kernel<<<NBLK, BLOCK, 0, stream>>>(x, qcodes, scales, zeros, bias, out);
}